// Round 6
// baseline (358.151 us; speedup 1.0000x reference)
//
#include <hip/hip_runtime.h>
#include <cstdint>

#define DEVI __device__ __forceinline__

typedef __bf16 bf16;
typedef __bf16 bf16x8 __attribute__((ext_vector_type(8)));
typedef __bf16 bf16x4 __attribute__((ext_vector_type(4)));
typedef __bf16 bf16x2 __attribute__((ext_vector_type(2)));
typedef float floatx4 __attribute__((ext_vector_type(4)));

constexpr int BATCH = 16, SEQ = 2048, DM = 256, DI = 512;
constexpr int M = BATCH * SEQ;   // 32768 rows
constexpr int NC = 64;           // scan chunks per sequence
constexpr int CL = SEQ / NC;     // 32 steps per chunk
static_assert(NC * CL == SEQ, "chunking");
constexpr float LOG2E = 1.4426950408889634f;

// ---- async global->LDS (16B per lane, wave-uniform base + lane*16) ----
DEVI void gl2lds16(const void* g, void* l) {
  __builtin_amdgcn_global_load_lds(
      (const __attribute__((address_space(1))) unsigned int*)(uintptr_t)g,
      (__attribute__((address_space(3))) unsigned int*)(unsigned int)(uintptr_t)l,
      16, 0, 0);
}

DEVI float sigmoidf_(float x) { return 1.f / (1.f + __expf(-x)); }
// native v_exp_f32 (computes 2^x). NOTE: "__exp2f" collides with glibc math.h macros.
DEVI float exp2_(float x) { return __builtin_amdgcn_exp2f(x); }

// =================== prep: weights fp32 -> bf16, A2 = -exp(A_log)*log2e, power-law flag ===================
__global__ __launch_bounds__(256) void prep_kernel(
    const float* __restrict__ w1, const float* __restrict__ wx,
    const float* __restrict__ wo, const float* __restrict__ alog,
    bf16* __restrict__ w1b, bf16* __restrict__ wxb, bf16* __restrict__ wob,
    float* __restrict__ An, int* __restrict__ flags) {
  constexpr int n1 = 1024 * 256, n2 = 48 * 512, n3 = 256 * 512;
  int i = blockIdx.x * 256 + threadIdx.x;
  if (i < n1) w1b[i] = (bf16)w1[i];
  else if (i < n1 + n2) wxb[i - n1] = (bf16)wx[i - n1];
  else if (i < n1 + n2 + n3) wob[i - n1 - n2] = (bf16)wo[i - n1 - n2];
  else if (i < n1 + n2 + n3 + DI) {
    const int e = i - (n1 + n2 + n3);
    const float a0 = -__expf(alog[e * 16]);
    bool ok = (a0 < 0.f);
#pragma unroll 1
    for (int s = 0; s < 16; s++) {
      const float a = -__expf(alog[e * 16 + s]);
      An[e * 16 + s] = a * LOG2E;
      ok = ok && (__builtin_fabsf(a / a0 - (float)(s + 1)) < 1e-3f);
    }
    flags[e] = ok ? 1 : 0;
  }
}

// =================== LayerNorm: one wave per 256-col row, bf16 out ===================
__global__ __launch_bounds__(256) void ln_kernel(
    const float* __restrict__ x, const float* __restrict__ w,
    const float* __restrict__ b, bf16* __restrict__ xn) {
  const int row = blockIdx.x * 4 + (threadIdx.x >> 6);
  const int lane = threadIdx.x & 63;
  const float4 v = ((const float4*)(x + (size_t)row * DM))[lane];
  float s = v.x + v.y + v.z + v.w;
  float s2 = v.x * v.x + v.y * v.y + v.z * v.z + v.w * v.w;
#pragma unroll
  for (int m = 1; m < 64; m <<= 1) { s += __shfl_xor(s, m); s2 += __shfl_xor(s2, m); }
  const float mu = s * (1.f / DM);
  const float var = s2 * (1.f / DM) - mu * mu;
  const float rs = rsqrtf(var + 1e-5f);
  const float4 wv = ((const float4*)w)[lane];
  const float4 bv = ((const float4*)b)[lane];
  bf16x4 o;
  o[0] = (bf16)((v.x - mu) * rs * wv.x + bv.x);
  o[1] = (bf16)((v.y - mu) * rs * wv.y + bv.y);
  o[2] = (bf16)((v.z - mu) * rs * wv.z + bv.z);
  o[3] = (bf16)((v.w - mu) * rs * wv.w + bv.w);
  *(bf16x4*)(xn + (size_t)row * DM + lane * 4) = o;
}

// =================== NT bf16 GEMM: C[M,N] = A[M,K] * W[N,K]^T (m97 structure) ===================
template <int N, int K, bool OUT_BF16, bool RESID>
__global__ __launch_bounds__(256) void gemm_nt(const bf16* __restrict__ A,
                                               const bf16* __restrict__ W,
                                               void* __restrict__ out,
                                               const float* __restrict__ resid) {
  constexpr int BK = 32;
  __shared__ __align__(16) bf16 lA[128 * BK];
  __shared__ __align__(16) bf16 lB[128 * BK];
  const int tid = threadIdx.x;
  const int wave = tid >> 6, lane = tid & 63;
  const int bm = blockIdx.x * 128, bn = blockIdx.y * 128;
  const int wm = (wave >> 1) * 64, wn = (wave & 1) * 64;
  const int q = lane >> 4, r = lane & 15;
  floatx4 acc[4][4] = {};
  const int c0 = wave * 64 + lane;
  const int row0 = c0 >> 2, kp = (c0 & 3) * 8;
  for (int k0 = 0; k0 < K; k0 += BK) {
    gl2lds16(A + (size_t)(bm + row0) * K + k0 + kp, lA + c0 * 8);
    gl2lds16(A + (size_t)(bm + row0 + 64) * K + k0 + kp, lA + (c0 + 256) * 8);
    gl2lds16(W + (size_t)(bn + row0) * K + k0 + kp, lB + c0 * 8);
    gl2lds16(W + (size_t)(bn + row0 + 64) * K + k0 + kp, lB + (c0 + 256) * 8);
    __syncthreads();
    bf16x8 af[4], bfr[4];
#pragma unroll
    for (int i = 0; i < 4; i++) af[i] = *(const bf16x8*)&lA[(wm + i * 16 + r) * BK + q * 8];
#pragma unroll
    for (int j = 0; j < 4; j++) bfr[j] = *(const bf16x8*)&lB[(wn + j * 16 + r) * BK + q * 8];
#pragma unroll
    for (int i = 0; i < 4; i++)
#pragma unroll
      for (int j = 0; j < 4; j++)
        acc[i][j] = __builtin_amdgcn_mfma_f32_16x16x32_bf16(af[i], bfr[j], acc[i][j], 0, 0, 0);
    __syncthreads();
  }
#pragma unroll
  for (int i = 0; i < 4; i++)
#pragma unroll
    for (int j = 0; j < 4; j++)
#pragma unroll
      for (int t = 0; t < 4; t++) {
        const int row = bm + wm + i * 16 + q * 4 + t;
        const int col = bn + wn + j * 16 + r;
        const size_t idx = (size_t)row * N + col;
        float v = acc[i][j][t];
        if constexpr (OUT_BF16) {
          ((bf16*)out)[idx] = (bf16)v;
        } else {
          if constexpr (RESID) v += resid[idx];
          ((float*)out)[idx] = v;
        }
      }
}

// =================== causal depthwise conv(4) + SiLU ===================
// thread = 2 adjacent e (packed 4B coalesced loads), 8 positions/thread.
__global__ __launch_bounds__(256) void conv_silu(const bf16* __restrict__ xz,
                                                 const float* __restrict__ cw,
                                                 const float* __restrict__ cb,
                                                 bf16* __restrict__ xc) {
  const int tid = threadIdx.x;
  const int e2 = tid * 2;              // [0,512) in steps of 2
  const int p0 = blockIdx.x * 8;
  const int b = blockIdx.y;
  const float4 w0 = ((const float4*)cw)[e2];
  const float4 w1 = ((const float4*)cw)[e2 + 1];
  const float2 bias = *(const float2*)(cb + e2);
  float xa[11], xb_[11];
#pragma unroll
  for (int j = 0; j < 11; j++) {
    const int pos = p0 - 3 + j;
    float fa = 0.f, fb = 0.f;
    if (pos >= 0) {  // block-uniform (only blockIdx.x==0 has pos<0)
      const unsigned u = *(const unsigned*)(xz + ((size_t)b * SEQ + pos) * 1024 + e2);
      fa = __uint_as_float(u << 16);
      fb = __uint_as_float(u & 0xFFFF0000u);
    }
    xa[j] = fa; xb_[j] = fb;
  }
#pragma unroll
  for (int k = 0; k < 8; k++) {
    const float a0 = bias.x + xa[k] * w0.x + xa[k + 1] * w0.y + xa[k + 2] * w0.z + xa[k + 3] * w0.w;
    const float a1 = bias.y + xb_[k] * w1.x + xb_[k + 1] * w1.y + xb_[k + 2] * w1.z + xb_[k + 3] * w1.w;
    bf16x2 o;
    o[0] = (bf16)(a0 * sigmoidf_(a0));
    o[1] = (bf16)(a1 * sigmoidf_(a1));
    *(bf16x2*)(xc + ((size_t)b * SEQ + p0 + k) * DI + e2) = o;
  }
}

// =================== x_proj: dbc[M,48] = xc[M,512] * Wx[48,512]^T ===================
// R6: 64-row tiles (512 blocks, was 256=1/CU), wave = 16 rows x 48 cols.
__global__ __launch_bounds__(256) void gemm_xproj(const bf16* __restrict__ A,
                                                  const bf16* __restrict__ W,
                                                  float* __restrict__ out) {
  constexpr int K = DI;
  __shared__ __align__(16) bf16 lW[48 * K];   // 49152 B
  __shared__ __align__(16) bf16 lA[64 * 32];  // 4096 B
  const int tid = threadIdx.x;
  const int wave = tid >> 6, lane = tid & 63;
  const int bm = blockIdx.x * 64;
  const int q = lane >> 4, r = lane & 15;
#pragma unroll
  for (int rd = 0; rd < 12; rd++) {  // 3072 chunks of 16B
    const int c = rd * 256 + tid;
    gl2lds16((const char*)W + (size_t)c * 16, (char*)lW + (size_t)c * 16);
  }
  const int row0 = tid >> 2, kp = (tid & 3) * 8;
  const int wm = wave * 16;
  floatx4 acc[3] = {};
  for (int k0 = 0; k0 < K; k0 += 32) {
    gl2lds16(A + (size_t)(bm + row0) * K + k0 + kp, lA + tid * 8);
    __syncthreads();
    bf16x8 af = *(const bf16x8*)&lA[(wm + r) * 32 + q * 8];
#pragma unroll
    for (int j = 0; j < 3; j++) {
      const bf16x8 bfr = *(const bf16x8*)&lW[(j * 16 + r) * K + k0 + q * 8];
      acc[j] = __builtin_amdgcn_mfma_f32_16x16x32_bf16(af, bfr, acc[j], 0, 0, 0);
    }
    __syncthreads();
  }
#pragma unroll
  for (int j = 0; j < 3; j++)
#pragma unroll
    for (int t = 0; t < 4; t++)
      out[(size_t)(bm + wm + q * 4 + t) * 48 + j * 16 + r] = acc[j][t];
}

// =================== dt_proj (K=16) + softplus -> bf16 ===================
__global__ __launch_bounds__(256) void dtproj_kernel(const float* __restrict__ dbc,
                                                     const float* __restrict__ dtw,
                                                     const float* __restrict__ dtb,
                                                     bf16* __restrict__ dt) {
  __shared__ __align__(16) float sd[64 * 16];
  const int tid = threadIdx.x;
  const int p0 = blockIdx.x * 64;
  const int e = blockIdx.y * 256 + tid;
  {
    const int rowi = tid >> 2, coli = (tid & 3) * 4;
    *(float4*)&sd[rowi * 16 + coli] = *(const float4*)(dbc + (size_t)(p0 + rowi) * 48 + coli);
  }
  float w[16];
#pragma unroll
  for (int s = 0; s < 16; s += 4) {
    float4 t4 = *(const float4*)(dtw + (size_t)e * 16 + s);
    w[s] = t4.x; w[s + 1] = t4.y; w[s + 2] = t4.z; w[s + 3] = t4.w;
  }
  const float bias = dtb[e];
  __syncthreads();
  for (int p = 0; p < 64; p++) {
    float s = bias;
#pragma unroll
    for (int r2 = 0; r2 < 16; r2++) s += sd[p * 16 + r2] * w[r2];
    const float sp = (s > 15.f) ? s : __logf(1.f + __expf(s));
    dt[(size_t)(p0 + p) * DI + e] = (bf16)sp;
  }
}

// =================== scan pass1: per-chunk aggregates ===================
// R6: 2 threads per (b,ch,e) chain, 8 states each. lo: d^1..8, hi: d^9..16.
__global__ __launch_bounds__(256) void scan_pass1(const bf16* __restrict__ dt,
                                                  const bf16* __restrict__ xc,
                                                  const float* __restrict__ dbc,
                                                  const float* __restrict__ An,
                                                  const int* __restrict__ flags,
                                                  float* __restrict__ U,
                                                  float* __restrict__ SD) {
  const int tid = threadIdx.x;
  const int e = blockIdx.x * 128 + (tid >> 1);
  const int half = tid & 1;
  const int ch = blockIdx.y, b = blockIdx.z;
  const int fast = flags[e];
  float h[8];
#pragma unroll
  for (int s = 0; s < 8; s++) h[s] = 0.f;
  float sdt = 0.f;
  const size_t posBase = (size_t)b * SEQ + (size_t)ch * CL;
  if (fast) {
    const float A0 = An[(size_t)e * 16];
    for (int il = 0; il < CL; il++) {
      const size_t pos = posBase + il;
      const float dtv = (float)dt[pos * DI + e];
      const float xv = (float)xc[pos * DI + e];
      const float* bc = dbc + pos * 48 + 16 + half * 8;
      float Bv[8];
#pragma unroll
      for (int s = 0; s < 8; s += 4) {
        float4 b4 = *(const float4*)(bc + s);
        Bv[s] = b4.x; Bv[s + 1] = b4.y; Bv[s + 2] = b4.z; Bv[s + 3] = b4.w;
      }
      const float dtx = dtv * xv;
      sdt += dtv;
      const float d1 = exp2_(dtv * A0);
      const float d2 = d1 * d1, d4 = d2 * d2, d8 = d4 * d4;
      float d = half ? d8 : 1.f;
#pragma unroll
      for (int s = 0; s < 8; s++) { d *= d1; h[s] = d * h[s] + dtx * Bv[s]; }
    }
  } else {
    float A[8];
#pragma unroll
    for (int s = 0; s < 8; s += 4) {
      float4 a4 = *(const float4*)(An + (size_t)e * 16 + half * 8 + s);
      A[s] = a4.x; A[s + 1] = a4.y; A[s + 2] = a4.z; A[s + 3] = a4.w;
    }
    for (int il = 0; il < CL; il++) {
      const size_t pos = posBase + il;
      const float dtv = (float)dt[pos * DI + e];
      const float xv = (float)xc[pos * DI + e];
      const float* bc = dbc + pos * 48 + 16 + half * 8;
      float Bv[8];
#pragma unroll
      for (int s = 0; s < 8; s += 4) {
        float4 b4 = *(const float4*)(bc + s);
        Bv[s] = b4.x; Bv[s + 1] = b4.y; Bv[s + 2] = b4.z; Bv[s + 3] = b4.w;
      }
      const float dtx = dtv * xv;
      sdt += dtv;
#pragma unroll
      for (int s = 0; s < 8; s++) h[s] = exp2_(dtv * A[s]) * h[s] + dtx * Bv[s];
    }
  }
  float* up = U + ((size_t)(b * NC + ch) * DI + e) * 16 + half * 8;
#pragma unroll
  for (int s = 0; s < 8; s += 4) {
    float4 o; o.x = h[s]; o.y = h[s + 1]; o.z = h[s + 2]; o.w = h[s + 3];
    *(float4*)(up + s) = o;
  }
  if (half == 0) SD[(size_t)(b * NC + ch) * DI + e] = sdt;
}

// =================== scan pass2: combine chunk aggregates, parallel over (b,e,s) ===================
__global__ __launch_bounds__(256) void scan_pass2(const float* __restrict__ SD,
                                                  float* U,
                                                  const float* __restrict__ An) {
  const int t = blockIdx.x * 256 + threadIdx.x;  // over BATCH*DI*16
  const int s = t & 15;
  const int e = (t >> 4) & (DI - 1);
  const int b = t >> 13;
  const float A = An[e * 16 + s];  // pre-scaled by log2e
  float h = 0.f;
  for (int c = 0; c < NC; c++) {
    const size_t cell = (size_t)(b * NC + c) * DI + e;
    const float sdv = SD[cell];
    const size_t base = cell * 16 + s;
    const float u = U[base];
    const float h0 = h;
    h = exp2_(A * sdv) * h0 + u;
    U[base] = h0;
  }
}

// =================== scan pass3: replay chunk from true h0, emit gated y ===================
// R6: 2 threads per chain (8 states each); y reduced via shfl_xor(1). yg aliases dt (safe:
// each thread-pair reads dt[pos*DI+e] before the lo thread writes the same index).
__global__ __launch_bounds__(256) void scan_pass3(const bf16* dt,
                                                  const bf16* __restrict__ xc,
                                                  const bf16* __restrict__ xz,
                                                  const float* __restrict__ dbc,
                                                  const float* __restrict__ An,
                                                  const int* __restrict__ flags,
                                                  const float* __restrict__ H0,
                                                  const float* __restrict__ Dp,
                                                  bf16* yg) {
  const int tid = threadIdx.x;
  const int e = blockIdx.x * 128 + (tid >> 1);
  const int half = tid & 1;
  const int ch = blockIdx.y, b = blockIdx.z;
  const int fast = flags[e];
  float h[8];
  const float* hp = H0 + ((size_t)(b * NC + ch) * DI + e) * 16 + half * 8;
#pragma unroll
  for (int s = 0; s < 8; s += 4) {
    float4 h4 = *(const float4*)(hp + s);
    h[s] = h4.x; h[s + 1] = h4.y; h[s + 2] = h4.z; h[s + 3] = h4.w;
  }
  const float Dv = Dp[e];
  const size_t posBase = (size_t)b * SEQ + (size_t)ch * CL;
  if (fast) {
    const float A0 = An[(size_t)e * 16];
    for (int il = 0; il < CL; il++) {
      const size_t pos = posBase + il;
      const float dtv = (float)dt[pos * DI + e];
      const float xv = (float)xc[pos * DI + e];
      const float zv = (float)xz[pos * 1024 + DI + e];
      const float* bc = dbc + pos * 48 + 16 + half * 8;
      float Bv[8], Cv[8];
#pragma unroll
      for (int s = 0; s < 8; s += 4) {
        float4 b4 = *(const float4*)(bc + s);
        Bv[s] = b4.x; Bv[s + 1] = b4.y; Bv[s + 2] = b4.z; Bv[s + 3] = b4.w;
        float4 c4 = *(const float4*)(bc + 16 + s);
        Cv[s] = c4.x; Cv[s + 1] = c4.y; Cv[s + 2] = c4.z; Cv[s + 3] = c4.w;
      }
      const float dtx = dtv * xv;
      const float d1 = exp2_(dtv * A0);
      const float d2 = d1 * d1, d4 = d2 * d2, d8 = d4 * d4;
      float d = half ? d8 : 1.f;
      float y = 0.f;
#pragma unroll
      for (int s = 0; s < 8; s++) {
        d *= d1;
        h[s] = d * h[s] + dtx * Bv[s];
        y += h[s] * Cv[s];
      }
      y += __shfl_xor(y, 1);
      const float yv = (y + Dv * xv) * zv * sigmoidf_(zv);
      if (half == 0) yg[pos * DI + e] = (bf16)yv;
    }
  } else {
    float A[8];
#pragma unroll
    for (int s = 0; s < 8; s += 4) {
      float4 a4 = *(const float4*)(An + (size_t)e * 16 + half * 8 + s);
      A[s] = a4.x; A[s + 1] = a4.y; A[s + 2] = a4.z; A[s + 3] = a4.w;
    }
    for (int il = 0; il < CL; il++) {
      const size_t pos = posBase + il;
      const float dtv = (float)dt[pos * DI + e];
      const float xv = (float)xc[pos * DI + e];
      const float zv = (float)xz[pos * 1024 + DI + e];
      const float* bc = dbc + pos * 48 + 16 + half * 8;
      float Bv[8], Cv[8];
#pragma unroll
      for (int s = 0; s < 8; s += 4) {
        float4 b4 = *(const float4*)(bc + s);
        Bv[s] = b4.x; Bv[s + 1] = b4.y; Bv[s + 2] = b4.z; Bv[s + 3] = b4.w;
        float4 c4 = *(const float4*)(bc + 16 + s);
        Cv[s] = c4.x; Cv[s + 1] = c4.y; Cv[s + 2] = c4.z; Cv[s + 3] = c4.w;
      }
      const float dtx = dtv * xv;
      float y = 0.f;
#pragma unroll
      for (int s = 0; s < 8; s++) {
        h[s] = exp2_(dtv * A[s]) * h[s] + dtx * Bv[s];
        y += h[s] * Cv[s];
      }
      y += __shfl_xor(y, 1);
      const float yv = (y + Dv * xv) * zv * sigmoidf_(zv);
      if (half == 0) yg[pos * DI + e] = (bf16)yv;
    }
  }
}

// =================== host ===================
extern "C" void kernel_launch(void* const* d_in, const int* in_sizes, int n_in,
                              void* d_out, int out_size, void* d_ws, size_t ws_size,
                              hipStream_t stream) {
  const float* x = (const float*)d_in[0];
  const float* ln_w = (const float*)d_in[1];
  const float* ln_b = (const float*)d_in[2];
  const float* w_in = (const float*)d_in[3];
  const float* conv_w = (const float*)d_in[4];
  const float* conv_b = (const float*)d_in[5];
  const float* w_x = (const float*)d_in[6];
  const float* w_dt = (const float*)d_in[7];
  const float* b_dt = (const float*)d_in[8];
  const float* a_log = (const float*)d_in[9];
  const float* d_par = (const float*)d_in[10];
  const float* w_out = (const float*)d_in[11];

  char* ws = (char*)d_ws;
  size_t off = 0;
  auto alloc = [&](size_t bytes) {
    void* p = ws + off;
    off = (off + bytes + 255) & ~(size_t)255;
    return p;
  };
  bf16* xn = (bf16*)alloc((size_t)M * DM * 2);
  bf16* xzb = (bf16*)alloc((size_t)M * 1024 * 2);
  bf16* xcb = (bf16*)alloc((size_t)M * DI * 2);
  float* dbc = (float*)alloc((size_t)M * 48 * 4);
  bf16* dtb_ = (bf16*)alloc((size_t)M * DI * 2);
  float* U = (float*)alloc((size_t)BATCH * NC * DI * 16 * 4);
  float* SD = (float*)alloc((size_t)BATCH * NC * DI * 4);
  bf16* w1b = (bf16*)alloc(1024 * 256 * 2);
  bf16* wxb = (bf16*)alloc(48 * 512 * 2);
  bf16* wob = (bf16*)alloc(256 * 512 * 2);
  float* An = (float*)alloc(512 * 16 * 4);
  int* flags = (int*)alloc(512 * 4);

  constexpr int prep_n = 1024 * 256 + 48 * 512 + 256 * 512 + DI;
  prep_kernel<<<dim3((prep_n + 255) / 256), dim3(256), 0, stream>>>(w_in, w_x, w_out, a_log, w1b, wxb, wob, An, flags);
  ln_kernel<<<dim3(M / 4), dim3(256), 0, stream>>>(x, ln_w, ln_b, xn);
  gemm_nt<1024, 256, true, false><<<dim3(M / 128, 8), dim3(256), 0, stream>>>(xn, w1b, (void*)xzb, nullptr);
  conv_silu<<<dim3(SEQ / 8, BATCH), dim3(256), 0, stream>>>(xzb, conv_w, conv_b, xcb);
  gemm_xproj<<<dim3(M / 64), dim3(256), 0, stream>>>(xcb, wxb, dbc);
  dtproj_kernel<<<dim3(M / 64, 2), dim3(256), 0, stream>>>(dbc, w_dt, b_dt, dtb_);
  scan_pass1<<<dim3(4, NC, BATCH), dim3(256), 0, stream>>>(dtb_, xcb, dbc, An, flags, U, SD);
  scan_pass2<<<dim3(BATCH * DI * 16 / 256), dim3(256), 0, stream>>>(SD, U, An);
  scan_pass3<<<dim3(4, NC, BATCH), dim3(256), 0, stream>>>(dtb_, xcb, xzb, dbc, An, flags, U, d_par, dtb_);
  gemm_nt<256, 512, false, true><<<dim3(M / 128, 2), dim3(256), 0, stream>>>(dtb_, wob, d_out, x);
}

// Round 7
// 319.897 us; speedup vs baseline: 1.1196x; 1.1196x over previous
//
#include <hip/hip_runtime.h>
#include <cstdint>

#define DEVI __device__ __forceinline__

typedef __bf16 bf16;
typedef __bf16 bf16x8 __attribute__((ext_vector_type(8)));
typedef __bf16 bf16x4 __attribute__((ext_vector_type(4)));
typedef __bf16 bf16x2 __attribute__((ext_vector_type(2)));
typedef float floatx4 __attribute__((ext_vector_type(4)));

constexpr int BATCH = 16, SEQ = 2048, DM = 256, DI = 512;
constexpr int M = BATCH * SEQ;   // 32768 rows
constexpr int NC = 128;          // scan chunks per sequence (R7: 64->128 for occupancy)
constexpr int CL = SEQ / NC;     // 16 steps per chunk
static_assert(NC * CL == SEQ, "chunking");
constexpr float LOG2E = 1.4426950408889634f;

// ---- async global->LDS (16B per lane, wave-uniform base + lane*16) ----
DEVI void gl2lds16(const void* g, void* l) {
  __builtin_amdgcn_global_load_lds(
      (const __attribute__((address_space(1))) unsigned int*)(uintptr_t)g,
      (__attribute__((address_space(3))) unsigned int*)(unsigned int)(uintptr_t)l,
      16, 0, 0);
}

DEVI float sigmoidf_(float x) { return 1.f / (1.f + __expf(-x)); }
// native v_exp_f32 (computes 2^x). NOTE: "__exp2f" collides with glibc math.h macros.
DEVI float exp2_(float x) { return __builtin_amdgcn_exp2f(x); }

// =================== prep: weights fp32 -> bf16, A2 = -exp(A_log)*log2e, power-law flag ===================
__global__ __launch_bounds__(256) void prep_kernel(
    const float* __restrict__ w1, const float* __restrict__ wx,
    const float* __restrict__ wo, const float* __restrict__ alog,
    bf16* __restrict__ w1b, bf16* __restrict__ wxb, bf16* __restrict__ wob,
    float* __restrict__ An, int* __restrict__ flags) {
  constexpr int n1 = 1024 * 256, n2 = 48 * 512, n3 = 256 * 512;
  int i = blockIdx.x * 256 + threadIdx.x;
  if (i < n1) w1b[i] = (bf16)w1[i];
  else if (i < n1 + n2) wxb[i - n1] = (bf16)wx[i - n1];
  else if (i < n1 + n2 + n3) wob[i - n1 - n2] = (bf16)wo[i - n1 - n2];
  else if (i < n1 + n2 + n3 + DI) {
    const int e = i - (n1 + n2 + n3);
    const float a0 = -__expf(alog[e * 16]);
    bool ok = (a0 < 0.f);
#pragma unroll 1
    for (int s = 0; s < 16; s++) {
      const float a = -__expf(alog[e * 16 + s]);
      An[e * 16 + s] = a * LOG2E;
      ok = ok && (__builtin_fabsf(a / a0 - (float)(s + 1)) < 1e-3f);
    }
    flags[e] = ok ? 1 : 0;
  }
}

// =================== LayerNorm: one wave per 256-col row, bf16 out ===================
__global__ __launch_bounds__(256) void ln_kernel(
    const float* __restrict__ x, const float* __restrict__ w,
    const float* __restrict__ b, bf16* __restrict__ xn) {
  const int row = blockIdx.x * 4 + (threadIdx.x >> 6);
  const int lane = threadIdx.x & 63;
  const float4 v = ((const float4*)(x + (size_t)row * DM))[lane];
  float s = v.x + v.y + v.z + v.w;
  float s2 = v.x * v.x + v.y * v.y + v.z * v.z + v.w * v.w;
#pragma unroll
  for (int m = 1; m < 64; m <<= 1) { s += __shfl_xor(s, m); s2 += __shfl_xor(s2, m); }
  const float mu = s * (1.f / DM);
  const float var = s2 * (1.f / DM) - mu * mu;
  const float rs = rsqrtf(var + 1e-5f);
  const float4 wv = ((const float4*)w)[lane];
  const float4 bv = ((const float4*)b)[lane];
  bf16x4 o;
  o[0] = (bf16)((v.x - mu) * rs * wv.x + bv.x);
  o[1] = (bf16)((v.y - mu) * rs * wv.y + bv.y);
  o[2] = (bf16)((v.z - mu) * rs * wv.z + bv.z);
  o[3] = (bf16)((v.w - mu) * rs * wv.w + bv.w);
  *(bf16x4*)(xn + (size_t)row * DM + lane * 4) = o;
}

// =================== NT bf16 GEMM: C[M,N] = A[M,K] * W[N,K]^T (m97 structure) ===================
template <int N, int K, bool OUT_BF16, bool RESID>
__global__ __launch_bounds__(256) void gemm_nt(const bf16* __restrict__ A,
                                               const bf16* __restrict__ W,
                                               void* __restrict__ out,
                                               const float* __restrict__ resid) {
  constexpr int BK = 32;
  __shared__ __align__(16) bf16 lA[128 * BK];
  __shared__ __align__(16) bf16 lB[128 * BK];
  const int tid = threadIdx.x;
  const int wave = tid >> 6, lane = tid & 63;
  const int bm = blockIdx.x * 128, bn = blockIdx.y * 128;
  const int wm = (wave >> 1) * 64, wn = (wave & 1) * 64;
  const int q = lane >> 4, r = lane & 15;
  floatx4 acc[4][4] = {};
  const int c0 = wave * 64 + lane;
  const int row0 = c0 >> 2, kp = (c0 & 3) * 8;
  for (int k0 = 0; k0 < K; k0 += BK) {
    gl2lds16(A + (size_t)(bm + row0) * K + k0 + kp, lA + c0 * 8);
    gl2lds16(A + (size_t)(bm + row0 + 64) * K + k0 + kp, lA + (c0 + 256) * 8);
    gl2lds16(W + (size_t)(bn + row0) * K + k0 + kp, lB + c0 * 8);
    gl2lds16(W + (size_t)(bn + row0 + 64) * K + k0 + kp, lB + (c0 + 256) * 8);
    __syncthreads();
    bf16x8 af[4], bfr[4];
#pragma unroll
    for (int i = 0; i < 4; i++) af[i] = *(const bf16x8*)&lA[(wm + i * 16 + r) * BK + q * 8];
#pragma unroll
    for (int j = 0; j < 4; j++) bfr[j] = *(const bf16x8*)&lB[(wn + j * 16 + r) * BK + q * 8];
#pragma unroll
    for (int i = 0; i < 4; i++)
#pragma unroll
      for (int j = 0; j < 4; j++)
        acc[i][j] = __builtin_amdgcn_mfma_f32_16x16x32_bf16(af[i], bfr[j], acc[i][j], 0, 0, 0);
    __syncthreads();
  }
#pragma unroll
  for (int i = 0; i < 4; i++)
#pragma unroll
    for (int j = 0; j < 4; j++)
#pragma unroll
      for (int t = 0; t < 4; t++) {
        const int row = bm + wm + i * 16 + q * 4 + t;
        const int col = bn + wn + j * 16 + r;
        const size_t idx = (size_t)row * N + col;
        float v = acc[i][j][t];
        if constexpr (OUT_BF16) {
          ((bf16*)out)[idx] = (bf16)v;
        } else {
          if constexpr (RESID) v += resid[idx];
          ((float*)out)[idx] = v;
        }
      }
}

// =================== causal depthwise conv(4) + SiLU ===================
// thread = 2 adjacent e (packed 4B coalesced loads), 8 positions/thread.
__global__ __launch_bounds__(256) void conv_silu(const bf16* __restrict__ xz,
                                                 const float* __restrict__ cw,
                                                 const float* __restrict__ cb,
                                                 bf16* __restrict__ xc) {
  const int tid = threadIdx.x;
  const int e2 = tid * 2;              // [0,512) in steps of 2
  const int p0 = blockIdx.x * 8;
  const int b = blockIdx.y;
  const float4 w0 = ((const float4*)cw)[e2];
  const float4 w1 = ((const float4*)cw)[e2 + 1];
  const float2 bias = *(const float2*)(cb + e2);
  float xa[11], xb_[11];
#pragma unroll
  for (int j = 0; j < 11; j++) {
    const int pos = p0 - 3 + j;
    float fa = 0.f, fb = 0.f;
    if (pos >= 0) {  // block-uniform (only blockIdx.x==0 has pos<0)
      const unsigned u = *(const unsigned*)(xz + ((size_t)b * SEQ + pos) * 1024 + e2);
      fa = __uint_as_float(u << 16);
      fb = __uint_as_float(u & 0xFFFF0000u);
    }
    xa[j] = fa; xb_[j] = fb;
  }
#pragma unroll
  for (int k = 0; k < 8; k++) {
    const float a0 = bias.x + xa[k] * w0.x + xa[k + 1] * w0.y + xa[k + 2] * w0.z + xa[k + 3] * w0.w;
    const float a1 = bias.y + xb_[k] * w1.x + xb_[k + 1] * w1.y + xb_[k + 2] * w1.z + xb_[k + 3] * w1.w;
    bf16x2 o;
    o[0] = (bf16)(a0 * sigmoidf_(a0));
    o[1] = (bf16)(a1 * sigmoidf_(a1));
    *(bf16x2*)(xc + ((size_t)b * SEQ + p0 + k) * DI + e2) = o;
  }
}

// =================== x_proj: dbc[M,48] = xc[M,512] * Wx[48,512]^T ===================
// 64-row tiles (512 blocks), wave = 16 rows x 48 cols.
__global__ __launch_bounds__(256) void gemm_xproj(const bf16* __restrict__ A,
                                                  const bf16* __restrict__ W,
                                                  float* __restrict__ out) {
  constexpr int K = DI;
  __shared__ __align__(16) bf16 lW[48 * K];   // 49152 B
  __shared__ __align__(16) bf16 lA[64 * 32];  // 4096 B
  const int tid = threadIdx.x;
  const int wave = tid >> 6, lane = tid & 63;
  const int bm = blockIdx.x * 64;
  const int q = lane >> 4, r = lane & 15;
#pragma unroll
  for (int rd = 0; rd < 12; rd++) {  // 3072 chunks of 16B
    const int c = rd * 256 + tid;
    gl2lds16((const char*)W + (size_t)c * 16, (char*)lW + (size_t)c * 16);
  }
  const int row0 = tid >> 2, kp = (tid & 3) * 8;
  const int wm = wave * 16;
  floatx4 acc[3] = {};
  for (int k0 = 0; k0 < K; k0 += 32) {
    gl2lds16(A + (size_t)(bm + row0) * K + k0 + kp, lA + tid * 8);
    __syncthreads();
    bf16x8 af = *(const bf16x8*)&lA[(wm + r) * 32 + q * 8];
#pragma unroll
    for (int j = 0; j < 3; j++) {
      const bf16x8 bfr = *(const bf16x8*)&lW[(j * 16 + r) * K + k0 + q * 8];
      acc[j] = __builtin_amdgcn_mfma_f32_16x16x32_bf16(af, bfr, acc[j], 0, 0, 0);
    }
    __syncthreads();
  }
#pragma unroll
  for (int j = 0; j < 3; j++)
#pragma unroll
    for (int t = 0; t < 4; t++)
      out[(size_t)(bm + wm + q * 4 + t) * 48 + j * 16 + r] = acc[j][t];
}

// =================== dt_proj (K=16) + softplus -> bf16 ===================
__global__ __launch_bounds__(256) void dtproj_kernel(const float* __restrict__ dbc,
                                                     const float* __restrict__ dtw,
                                                     const float* __restrict__ dtb,
                                                     bf16* __restrict__ dt) {
  __shared__ __align__(16) float sd[64 * 16];
  const int tid = threadIdx.x;
  const int p0 = blockIdx.x * 64;
  const int e = blockIdx.y * 256 + tid;
  {
    const int rowi = tid >> 2, coli = (tid & 3) * 4;
    *(float4*)&sd[rowi * 16 + coli] = *(const float4*)(dbc + (size_t)(p0 + rowi) * 48 + coli);
  }
  float w[16];
#pragma unroll
  for (int s = 0; s < 16; s += 4) {
    float4 t4 = *(const float4*)(dtw + (size_t)e * 16 + s);
    w[s] = t4.x; w[s + 1] = t4.y; w[s + 2] = t4.z; w[s + 3] = t4.w;
  }
  const float bias = dtb[e];
  __syncthreads();
  for (int p = 0; p < 64; p++) {
    float s = bias;
#pragma unroll
    for (int r2 = 0; r2 < 16; r2++) s += sd[p * 16 + r2] * w[r2];
    const float sp = (s > 15.f) ? s : __logf(1.f + __expf(s));
    dt[(size_t)(p0 + p) * DI + e] = (bf16)sp;
  }
}

// =================== scan pass1: per-chunk aggregates (R5 structure, 1 thread = 1 chain) ===================
__global__ __launch_bounds__(256) void scan_pass1(const bf16* __restrict__ dt,
                                                  const bf16* __restrict__ xc,
                                                  const float* __restrict__ dbc,
                                                  const float* __restrict__ An,
                                                  const int* __restrict__ flags,
                                                  float* __restrict__ U,
                                                  float* __restrict__ SD) {
  const int e = blockIdx.x * 256 + threadIdx.x;
  const int ch = blockIdx.y, b = blockIdx.z;
  const int fast = flags[e];
  float h[16];
#pragma unroll
  for (int s = 0; s < 16; s++) h[s] = 0.f;
  float sdt = 0.f;
  const size_t posBase = (size_t)b * SEQ + (size_t)ch * CL;
  if (fast) {
    const float A0 = An[(size_t)e * 16];
    for (int il = 0; il < CL; il++) {
      const size_t pos = posBase + il;
      const float dtv = (float)dt[pos * DI + e];
      const float xv = (float)xc[pos * DI + e];
      const float* bc = dbc + pos * 48 + 16;
      float Bv[16];
#pragma unroll
      for (int s = 0; s < 16; s += 4) {
        float4 b4 = *(const float4*)(bc + s);
        Bv[s] = b4.x; Bv[s + 1] = b4.y; Bv[s + 2] = b4.z; Bv[s + 3] = b4.w;
      }
      const float dtx = dtv * xv;
      sdt += dtv;
      const float d1 = exp2_(dtv * A0);
      float d = 1.f;
#pragma unroll
      for (int s = 0; s < 16; s++) { d *= d1; h[s] = d * h[s] + dtx * Bv[s]; }
    }
  } else {
    float A[16];
#pragma unroll
    for (int s = 0; s < 16; s += 4) {
      float4 a4 = *(const float4*)(An + (size_t)e * 16 + s);
      A[s] = a4.x; A[s + 1] = a4.y; A[s + 2] = a4.z; A[s + 3] = a4.w;
    }
    for (int il = 0; il < CL; il++) {
      const size_t pos = posBase + il;
      const float dtv = (float)dt[pos * DI + e];
      const float xv = (float)xc[pos * DI + e];
      const float* bc = dbc + pos * 48 + 16;
      float Bv[16];
#pragma unroll
      for (int s = 0; s < 16; s += 4) {
        float4 b4 = *(const float4*)(bc + s);
        Bv[s] = b4.x; Bv[s + 1] = b4.y; Bv[s + 2] = b4.z; Bv[s + 3] = b4.w;
      }
      const float dtx = dtv * xv;
      sdt += dtv;
#pragma unroll
      for (int s = 0; s < 16; s++) h[s] = exp2_(dtv * A[s]) * h[s] + dtx * Bv[s];
    }
  }
  float* up = U + ((size_t)(b * NC + ch) * DI + e) * 16;
#pragma unroll
  for (int s = 0; s < 16; s += 4) {
    float4 o; o.x = h[s]; o.y = h[s + 1]; o.z = h[s + 2]; o.w = h[s + 3];
    *(float4*)(up + s) = o;
  }
  SD[(size_t)(b * NC + ch) * DI + e] = sdt;
}

// =================== scan pass2: combine chunk aggregates, parallel over (b,e,s) ===================
__global__ __launch_bounds__(256) void scan_pass2(const float* __restrict__ SD,
                                                  float* U,
                                                  const float* __restrict__ An) {
  const int t = blockIdx.x * 256 + threadIdx.x;  // over BATCH*DI*16
  const int s = t & 15;
  const int e = (t >> 4) & (DI - 1);
  const int b = t >> 13;
  const float A = An[e * 16 + s];  // pre-scaled by log2e
  float h = 0.f;
#pragma unroll 4
  for (int c = 0; c < NC; c++) {
    const size_t cell = (size_t)(b * NC + c) * DI + e;
    const float sdv = SD[cell];
    const size_t base = cell * 16 + s;
    const float u = U[base];
    const float h0 = h;
    h = exp2_(A * sdv) * h0 + u;
    U[base] = h0;
  }
}

// =================== scan pass3: replay chunk from true h0, emit gated y (yg aliases dt!) ===================
__global__ __launch_bounds__(256) void scan_pass3(const bf16* dt,
                                                  const bf16* __restrict__ xc,
                                                  const bf16* __restrict__ xz,
                                                  const float* __restrict__ dbc,
                                                  const float* __restrict__ An,
                                                  const int* __restrict__ flags,
                                                  const float* __restrict__ H0,
                                                  const float* __restrict__ Dp,
                                                  bf16* yg) {
  const int e = blockIdx.x * 256 + threadIdx.x;
  const int ch = blockIdx.y, b = blockIdx.z;
  const int fast = flags[e];
  float h[16];
  const float* hp = H0 + ((size_t)(b * NC + ch) * DI + e) * 16;
#pragma unroll
  for (int s = 0; s < 16; s += 4) {
    float4 h4 = *(const float4*)(hp + s);
    h[s] = h4.x; h[s + 1] = h4.y; h[s + 2] = h4.z; h[s + 3] = h4.w;
  }
  const float Dv = Dp[e];
  const size_t posBase = (size_t)b * SEQ + (size_t)ch * CL;
  if (fast) {
    const float A0 = An[(size_t)e * 16];
    for (int il = 0; il < CL; il++) {
      const size_t pos = posBase + il;
      const float dtv = (float)dt[pos * DI + e];
      const float xv = (float)xc[pos * DI + e];
      const float zv = (float)xz[pos * 1024 + DI + e];
      const float* bc = dbc + pos * 48 + 16;
      float Bv[16], Cv[16];
#pragma unroll
      for (int s = 0; s < 16; s += 4) {
        float4 b4 = *(const float4*)(bc + s);
        Bv[s] = b4.x; Bv[s + 1] = b4.y; Bv[s + 2] = b4.z; Bv[s + 3] = b4.w;
        float4 c4 = *(const float4*)(bc + 16 + s);
        Cv[s] = c4.x; Cv[s + 1] = c4.y; Cv[s + 2] = c4.z; Cv[s + 3] = c4.w;
      }
      const float dtx = dtv * xv;
      const float d1 = exp2_(dtv * A0);
      float d = 1.f, y = 0.f;
#pragma unroll
      for (int s = 0; s < 16; s++) {
        d *= d1;
        h[s] = d * h[s] + dtx * Bv[s];
        y += h[s] * Cv[s];
      }
      const float yv = (y + Dv * xv) * zv * sigmoidf_(zv);
      yg[pos * DI + e] = (bf16)yv;
    }
  } else {
    float A[16];
#pragma unroll
    for (int s = 0; s < 16; s += 4) {
      float4 a4 = *(const float4*)(An + (size_t)e * 16 + s);
      A[s] = a4.x; A[s + 1] = a4.y; A[s + 2] = a4.z; A[s + 3] = a4.w;
    }
    for (int il = 0; il < CL; il++) {
      const size_t pos = posBase + il;
      const float dtv = (float)dt[pos * DI + e];
      const float xv = (float)xc[pos * DI + e];
      const float zv = (float)xz[pos * 1024 + DI + e];
      const float* bc = dbc + pos * 48 + 16;
      float Bv[16], Cv[16];
#pragma unroll
      for (int s = 0; s < 16; s += 4) {
        float4 b4 = *(const float4*)(bc + s);
        Bv[s] = b4.x; Bv[s + 1] = b4.y; Bv[s + 2] = b4.z; Bv[s + 3] = b4.w;
        float4 c4 = *(const float4*)(bc + 16 + s);
        Cv[s] = c4.x; Cv[s + 1] = c4.y; Cv[s + 2] = c4.z; Cv[s + 3] = c4.w;
      }
      const float dtx = dtv * xv;
      float y = 0.f;
#pragma unroll
      for (int s = 0; s < 16; s++) {
        h[s] = exp2_(dtv * A[s]) * h[s] + dtx * Bv[s];
        y += h[s] * Cv[s];
      }
      const float yv = (y + Dv * xv) * zv * sigmoidf_(zv);
      yg[pos * DI + e] = (bf16)yv;
    }
  }
}

// =================== host ===================
extern "C" void kernel_launch(void* const* d_in, const int* in_sizes, int n_in,
                              void* d_out, int out_size, void* d_ws, size_t ws_size,
                              hipStream_t stream) {
  const float* x = (const float*)d_in[0];
  const float* ln_w = (const float*)d_in[1];
  const float* ln_b = (const float*)d_in[2];
  const float* w_in = (const float*)d_in[3];
  const float* conv_w = (const float*)d_in[4];
  const float* conv_b = (const float*)d_in[5];
  const float* w_x = (const float*)d_in[6];
  const float* w_dt = (const float*)d_in[7];
  const float* b_dt = (const float*)d_in[8];
  const float* a_log = (const float*)d_in[9];
  const float* d_par = (const float*)d_in[10];
  const float* w_out = (const float*)d_in[11];

  char* ws = (char*)d_ws;
  size_t off = 0;
  auto alloc = [&](size_t bytes) {
    void* p = ws + off;
    off = (off + bytes + 255) & ~(size_t)255;
    return p;
  };
  bf16* xn = (bf16*)alloc((size_t)M * DM * 2);
  bf16* xzb = (bf16*)alloc((size_t)M * 1024 * 2);
  bf16* xcb = (bf16*)alloc((size_t)M * DI * 2);
  float* dbc = (float*)alloc((size_t)M * 48 * 4);
  bf16* dtb_ = (bf16*)alloc((size_t)M * DI * 2);
  float* U = (float*)alloc((size_t)BATCH * NC * DI * 16 * 4);  // 67.1 MB
  float* SD = (float*)alloc((size_t)BATCH * NC * DI * 4);      // 4.2 MB
  bf16* w1b = (bf16*)alloc(1024 * 256 * 2);
  bf16* wxb = (bf16*)alloc(48 * 512 * 2);
  bf16* wob = (bf16*)alloc(256 * 512 * 2);
  float* An = (float*)alloc(512 * 16 * 4);
  int* flags = (int*)alloc(512 * 4);

  constexpr int prep_n = 1024 * 256 + 48 * 512 + 256 * 512 + DI;
  prep_kernel<<<dim3((prep_n + 255) / 256), dim3(256), 0, stream>>>(w_in, w_x, w_out, a_log, w1b, wxb, wob, An, flags);
  ln_kernel<<<dim3(M / 4), dim3(256), 0, stream>>>(x, ln_w, ln_b, xn);
  gemm_nt<1024, 256, true, false><<<dim3(M / 128, 8), dim3(256), 0, stream>>>(xn, w1b, (void*)xzb, nullptr);
  conv_silu<<<dim3(SEQ / 8, BATCH), dim3(256), 0, stream>>>(xzb, conv_w, conv_b, xcb);
  gemm_xproj<<<dim3(M / 64), dim3(256), 0, stream>>>(xcb, wxb, dbc);
  dtproj_kernel<<<dim3(M / 64, 2), dim3(256), 0, stream>>>(dbc, w_dt, b_dt, dtb_);
  scan_pass1<<<dim3(2, NC, BATCH), dim3(256), 0, stream>>>(dtb_, xcb, dbc, An, flags, U, SD);
  scan_pass2<<<dim3(BATCH * DI * 16 / 256), dim3(256), 0, stream>>>(SD, U, An);
  scan_pass3<<<dim3(2, NC, BATCH), dim3(256), 0, stream>>>(dtb_, xcb, xzb, dbc, An, flags, U, d_par, dtb_);
  gemm_nt<256, 512, false, true><<<dim3(M / 128, 2), dim3(256), 0, stream>>>(dtb_, wob, d_out, x);
}

// Round 8
// 312.901 us; speedup vs baseline: 1.1446x; 1.0224x over previous
//
#include <hip/hip_runtime.h>
#include <cstdint>

#define DEVI __device__ __forceinline__

typedef __bf16 bf16;
typedef __bf16 bf16x8 __attribute__((ext_vector_type(8)));
typedef __bf16 bf16x4 __attribute__((ext_vector_type(4)));
typedef __bf16 bf16x2 __attribute__((ext_vector_type(2)));
typedef float floatx4 __attribute__((ext_vector_type(4)));

constexpr int BATCH = 16, SEQ = 2048, DM = 256, DI = 512;
constexpr int M = BATCH * SEQ;   // 32768 rows
constexpr int NC = 64;           // scan chunks per sequence (R8: back to 64 — R7 showed 128 is net-negative)
constexpr int CL = SEQ / NC;     // 32 steps per chunk
static_assert(NC * CL == SEQ, "chunking");
constexpr float LOG2E = 1.4426950408889634f;

// ---- async global->LDS (16B per lane, wave-uniform base + lane*16) ----
DEVI void gl2lds16(const void* g, void* l) {
  __builtin_amdgcn_global_load_lds(
      (const __attribute__((address_space(1))) unsigned int*)(uintptr_t)g,
      (__attribute__((address_space(3))) unsigned int*)(unsigned int)(uintptr_t)l,
      16, 0, 0);
}

DEVI float sigmoidf_(float x) { return 1.f / (1.f + __expf(-x)); }
// native v_exp_f32 (computes 2^x). NOTE: "__exp2f" collides with glibc math.h macros.
DEVI float exp2_(float x) { return __builtin_amdgcn_exp2f(x); }

// =================== prep: weights fp32 -> bf16, A2 = -exp(A_log)*log2e, power-law flag ===================
__global__ __launch_bounds__(256) void prep_kernel(
    const float* __restrict__ w1, const float* __restrict__ wx,
    const float* __restrict__ wo, const float* __restrict__ alog,
    bf16* __restrict__ w1b, bf16* __restrict__ wxb, bf16* __restrict__ wob,
    float* __restrict__ An, int* __restrict__ flags) {
  constexpr int n1 = 1024 * 256, n2 = 48 * 512, n3 = 256 * 512;
  int i = blockIdx.x * 256 + threadIdx.x;
  if (i < n1) w1b[i] = (bf16)w1[i];
  else if (i < n1 + n2) wxb[i - n1] = (bf16)wx[i - n1];
  else if (i < n1 + n2 + n3) wob[i - n1 - n2] = (bf16)wo[i - n1 - n2];
  else if (i < n1 + n2 + n3 + DI) {
    const int e = i - (n1 + n2 + n3);
    const float a0 = -__expf(alog[e * 16]);
    bool ok = (a0 < 0.f);
#pragma unroll 1
    for (int s = 0; s < 16; s++) {
      const float a = -__expf(alog[e * 16 + s]);
      An[e * 16 + s] = a * LOG2E;
      ok = ok && (__builtin_fabsf(a / a0 - (float)(s + 1)) < 1e-3f);
    }
    flags[e] = ok ? 1 : 0;
  }
}

// =================== LayerNorm: one wave per 256-col row, bf16 out ===================
__global__ __launch_bounds__(256) void ln_kernel(
    const float* __restrict__ x, const float* __restrict__ w,
    const float* __restrict__ b, bf16* __restrict__ xn) {
  const int row = blockIdx.x * 4 + (threadIdx.x >> 6);
  const int lane = threadIdx.x & 63;
  const float4 v = ((const float4*)(x + (size_t)row * DM))[lane];
  float s = v.x + v.y + v.z + v.w;
  float s2 = v.x * v.x + v.y * v.y + v.z * v.z + v.w * v.w;
#pragma unroll
  for (int m = 1; m < 64; m <<= 1) { s += __shfl_xor(s, m); s2 += __shfl_xor(s2, m); }
  const float mu = s * (1.f / DM);
  const float var = s2 * (1.f / DM) - mu * mu;
  const float rs = rsqrtf(var + 1e-5f);
  const float4 wv = ((const float4*)w)[lane];
  const float4 bv = ((const float4*)b)[lane];
  bf16x4 o;
  o[0] = (bf16)((v.x - mu) * rs * wv.x + bv.x);
  o[1] = (bf16)((v.y - mu) * rs * wv.y + bv.y);
  o[2] = (bf16)((v.z - mu) * rs * wv.z + bv.z);
  o[3] = (bf16)((v.w - mu) * rs * wv.w + bv.w);
  *(bf16x4*)(xn + (size_t)row * DM + lane * 4) = o;
}

// =================== NT bf16 GEMM: C[M,N] = A[M,K] * W[N,K]^T (m97 structure) ===================
template <int N, int K, bool OUT_BF16, bool RESID>
__global__ __launch_bounds__(256) void gemm_nt(const bf16* __restrict__ A,
                                               const bf16* __restrict__ W,
                                               void* __restrict__ out,
                                               const float* __restrict__ resid) {
  constexpr int BK = 32;
  __shared__ __align__(16) bf16 lA[128 * BK];
  __shared__ __align__(16) bf16 lB[128 * BK];
  const int tid = threadIdx.x;
  const int wave = tid >> 6, lane = tid & 63;
  const int bm = blockIdx.x * 128, bn = blockIdx.y * 128;
  const int wm = (wave >> 1) * 64, wn = (wave & 1) * 64;
  const int q = lane >> 4, r = lane & 15;
  floatx4 acc[4][4] = {};
  const int c0 = wave * 64 + lane;
  const int row0 = c0 >> 2, kp = (c0 & 3) * 8;
  for (int k0 = 0; k0 < K; k0 += BK) {
    gl2lds16(A + (size_t)(bm + row0) * K + k0 + kp, lA + c0 * 8);
    gl2lds16(A + (size_t)(bm + row0 + 64) * K + k0 + kp, lA + (c0 + 256) * 8);
    gl2lds16(W + (size_t)(bn + row0) * K + k0 + kp, lB + c0 * 8);
    gl2lds16(W + (size_t)(bn + row0 + 64) * K + k0 + kp, lB + (c0 + 256) * 8);
    __syncthreads();
    bf16x8 af[4], bfr[4];
#pragma unroll
    for (int i = 0; i < 4; i++) af[i] = *(const bf16x8*)&lA[(wm + i * 16 + r) * BK + q * 8];
#pragma unroll
    for (int j = 0; j < 4; j++) bfr[j] = *(const bf16x8*)&lB[(wn + j * 16 + r) * BK + q * 8];
#pragma unroll
    for (int i = 0; i < 4; i++)
#pragma unroll
      for (int j = 0; j < 4; j++)
        acc[i][j] = __builtin_amdgcn_mfma_f32_16x16x32_bf16(af[i], bfr[j], acc[i][j], 0, 0, 0);
    __syncthreads();
  }
#pragma unroll
  for (int i = 0; i < 4; i++)
#pragma unroll
    for (int j = 0; j < 4; j++)
#pragma unroll
      for (int t = 0; t < 4; t++) {
        const int row = bm + wm + i * 16 + q * 4 + t;
        const int col = bn + wn + j * 16 + r;
        const size_t idx = (size_t)row * N + col;
        float v = acc[i][j][t];
        if constexpr (OUT_BF16) {
          ((bf16*)out)[idx] = (bf16)v;
        } else {
          if constexpr (RESID) v += resid[idx];
          ((float*)out)[idx] = v;
        }
      }
}

// =================== causal depthwise conv(4) + SiLU ===================
// thread = 2 adjacent e (packed 4B coalesced loads), 8 positions/thread.
__global__ __launch_bounds__(256) void conv_silu(const bf16* __restrict__ xz,
                                                 const float* __restrict__ cw,
                                                 const float* __restrict__ cb,
                                                 bf16* __restrict__ xc) {
  const int tid = threadIdx.x;
  const int e2 = tid * 2;              // [0,512) in steps of 2
  const int p0 = blockIdx.x * 8;
  const int b = blockIdx.y;
  const float4 w0 = ((const float4*)cw)[e2];
  const float4 w1 = ((const float4*)cw)[e2 + 1];
  const float2 bias = *(const float2*)(cb + e2);
  float xa[11], xb_[11];
#pragma unroll
  for (int j = 0; j < 11; j++) {
    const int pos = p0 - 3 + j;
    float fa = 0.f, fb = 0.f;
    if (pos >= 0) {  // block-uniform (only blockIdx.x==0 has pos<0)
      const unsigned u = *(const unsigned*)(xz + ((size_t)b * SEQ + pos) * 1024 + e2);
      fa = __uint_as_float(u << 16);
      fb = __uint_as_float(u & 0xFFFF0000u);
    }
    xa[j] = fa; xb_[j] = fb;
  }
#pragma unroll
  for (int k = 0; k < 8; k++) {
    const float a0 = bias.x + xa[k] * w0.x + xa[k + 1] * w0.y + xa[k + 2] * w0.z + xa[k + 3] * w0.w;
    const float a1 = bias.y + xb_[k] * w1.x + xb_[k + 1] * w1.y + xb_[k + 2] * w1.z + xb_[k + 3] * w1.w;
    bf16x2 o;
    o[0] = (bf16)(a0 * sigmoidf_(a0));
    o[1] = (bf16)(a1 * sigmoidf_(a1));
    *(bf16x2*)(xc + ((size_t)b * SEQ + p0 + k) * DI + e2) = o;
  }
}

// =================== x_proj: dbc[M,48] = xc[M,512] * Wx[48,512]^T ===================
// 64-row tiles (512 blocks), wave = 16 rows x 48 cols.
__global__ __launch_bounds__(256) void gemm_xproj(const bf16* __restrict__ A,
                                                  const bf16* __restrict__ W,
                                                  float* __restrict__ out) {
  constexpr int K = DI;
  __shared__ __align__(16) bf16 lW[48 * K];   // 49152 B
  __shared__ __align__(16) bf16 lA[64 * 32];  // 4096 B
  const int tid = threadIdx.x;
  const int wave = tid >> 6, lane = tid & 63;
  const int bm = blockIdx.x * 64;
  const int q = lane >> 4, r = lane & 15;
#pragma unroll
  for (int rd = 0; rd < 12; rd++) {  // 3072 chunks of 16B
    const int c = rd * 256 + tid;
    gl2lds16((const char*)W + (size_t)c * 16, (char*)lW + (size_t)c * 16);
  }
  const int row0 = tid >> 2, kp = (tid & 3) * 8;
  const int wm = wave * 16;
  floatx4 acc[3] = {};
  for (int k0 = 0; k0 < K; k0 += 32) {
    gl2lds16(A + (size_t)(bm + row0) * K + k0 + kp, lA + tid * 8);
    __syncthreads();
    bf16x8 af = *(const bf16x8*)&lA[(wm + r) * 32 + q * 8];
#pragma unroll
    for (int j = 0; j < 3; j++) {
      const bf16x8 bfr = *(const bf16x8*)&lW[(j * 16 + r) * K + k0 + q * 8];
      acc[j] = __builtin_amdgcn_mfma_f32_16x16x32_bf16(af, bfr, acc[j], 0, 0, 0);
    }
    __syncthreads();
  }
#pragma unroll
  for (int j = 0; j < 3; j++)
#pragma unroll
    for (int t = 0; t < 4; t++)
      out[(size_t)(bm + wm + q * 4 + t) * 48 + j * 16 + r] = acc[j][t];
}

// =================== dt_proj (K=16) + softplus -> bf16 ===================
__global__ __launch_bounds__(256) void dtproj_kernel(const float* __restrict__ dbc,
                                                     const float* __restrict__ dtw,
                                                     const float* __restrict__ dtb,
                                                     bf16* __restrict__ dt) {
  __shared__ __align__(16) float sd[64 * 16];
  const int tid = threadIdx.x;
  const int p0 = blockIdx.x * 64;
  const int e = blockIdx.y * 256 + tid;
  {
    const int rowi = tid >> 2, coli = (tid & 3) * 4;
    *(float4*)&sd[rowi * 16 + coli] = *(const float4*)(dbc + (size_t)(p0 + rowi) * 48 + coli);
  }
  float w[16];
#pragma unroll
  for (int s = 0; s < 16; s += 4) {
    float4 t4 = *(const float4*)(dtw + (size_t)e * 16 + s);
    w[s] = t4.x; w[s + 1] = t4.y; w[s + 2] = t4.z; w[s + 3] = t4.w;
  }
  const float bias = dtb[e];
  __syncthreads();
  for (int p = 0; p < 64; p++) {
    float s = bias;
#pragma unroll
    for (int r2 = 0; r2 < 16; r2++) s += sd[p * 16 + r2] * w[r2];
    const float sp = (s > 15.f) ? s : __logf(1.f + __expf(s));
    dt[(size_t)(p0 + p) * DI + e] = (bf16)sp;
  }
}

// ---- power tree: P[s] = d1^(s+1), depth 4 ----
DEVI void powtree(float d1, float* P) {
  const float p2 = d1 * d1, p4 = p2 * p2, p8 = p4 * p4;
  P[0] = d1;      P[1] = p2;      P[2] = p2 * d1; P[3] = p4;
  P[4] = p4 * d1; P[5] = p4 * p2; P[6] = p4 * P[2]; P[7] = p8;
  P[8] = p8 * d1; P[9] = p8 * p2; P[10] = p8 * P[2]; P[11] = p8 * p4;
  P[12] = p8 * P[4]; P[13] = p8 * P[5]; P[14] = p8 * P[6]; P[15] = p8 * p8;
}

// =================== scan pass1: per-chunk aggregates (B/C staged in LDS) ===================
__global__ __launch_bounds__(256) void scan_pass1(const bf16* __restrict__ dt,
                                                  const bf16* __restrict__ xc,
                                                  const float* __restrict__ dbc,
                                                  const float* __restrict__ An,
                                                  const int* __restrict__ flags,
                                                  float* __restrict__ U,
                                                  float* __restrict__ SD) {
  __shared__ __align__(16) float sbc[CL * 32];  // per pos: B[16] C[16]
  const int tid = threadIdx.x;
  const int e = blockIdx.x * 256 + tid;
  const int ch = blockIdx.y, b = blockIdx.z;
  const size_t posBase = (size_t)b * SEQ + (size_t)ch * CL;
  {
    const int il = tid >> 3, f = (tid & 7) * 4;
    gl2lds16(dbc + (posBase + il) * 48 + 16 + f, (char*)sbc + tid * 16);
  }
  const int fast = flags[e];
  float h[16];
#pragma unroll
  for (int s = 0; s < 16; s++) h[s] = 0.f;
  float sdt = 0.f;
  const float A0 = An[(size_t)e * 16];
  float A[16];
  if (!fast) {
#pragma unroll
    for (int s = 0; s < 16; s += 4) {
      float4 a4 = *(const float4*)(An + (size_t)e * 16 + s);
      A[s] = a4.x; A[s + 1] = a4.y; A[s + 2] = a4.z; A[s + 3] = a4.w;
    }
  }
  __syncthreads();
  if (fast) {
#pragma unroll 2
    for (int il = 0; il < CL; il++) {
      const size_t pos = posBase + il;
      const float dtv = (float)dt[pos * DI + e];
      const float xv = (float)xc[pos * DI + e];
      const float dtx = dtv * xv;
      sdt += dtv;
      float P[16];
      powtree(exp2_(dtv * A0), P);
      const float* bc = sbc + il * 32;
#pragma unroll
      for (int sg = 0; sg < 4; sg++) {
        const float4 B4 = *(const float4*)(bc + sg * 4);
        h[sg * 4 + 0] = P[sg * 4 + 0] * h[sg * 4 + 0] + dtx * B4.x;
        h[sg * 4 + 1] = P[sg * 4 + 1] * h[sg * 4 + 1] + dtx * B4.y;
        h[sg * 4 + 2] = P[sg * 4 + 2] * h[sg * 4 + 2] + dtx * B4.z;
        h[sg * 4 + 3] = P[sg * 4 + 3] * h[sg * 4 + 3] + dtx * B4.w;
      }
    }
  } else {
#pragma unroll 2
    for (int il = 0; il < CL; il++) {
      const size_t pos = posBase + il;
      const float dtv = (float)dt[pos * DI + e];
      const float xv = (float)xc[pos * DI + e];
      const float dtx = dtv * xv;
      sdt += dtv;
      const float* bc = sbc + il * 32;
#pragma unroll
      for (int s = 0; s < 16; s++) h[s] = exp2_(dtv * A[s]) * h[s] + dtx * bc[s];
    }
  }
  float* up = U + ((size_t)(b * NC + ch) * DI + e) * 16;
#pragma unroll
  for (int s = 0; s < 16; s += 4) {
    float4 o; o.x = h[s]; o.y = h[s + 1]; o.z = h[s + 2]; o.w = h[s + 3];
    *(float4*)(up + s) = o;
  }
  SD[(size_t)(b * NC + ch) * DI + e] = sdt;
}

// =================== scan pass2: combine chunk aggregates, parallel over (b,e,s) ===================
__global__ __launch_bounds__(256) void scan_pass2(const float* __restrict__ SD,
                                                  float* U,
                                                  const float* __restrict__ An) {
  const int t = blockIdx.x * 256 + threadIdx.x;  // over BATCH*DI*16
  const int s = t & 15;
  const int e = (t >> 4) & (DI - 1);
  const int b = t >> 13;
  const float A = An[e * 16 + s];  // pre-scaled by log2e
  float h = 0.f;
#pragma unroll 4
  for (int c = 0; c < NC; c++) {
    const size_t cell = (size_t)(b * NC + c) * DI + e;
    const float sdv = SD[cell];
    const size_t base = cell * 16 + s;
    const float u = U[base];
    const float h0 = h;
    h = exp2_(A * sdv) * h0 + u;
    U[base] = h0;
  }
}

// =================== scan pass3: replay chunk from true h0, emit gated y ===================
// R8: yg is a SEPARATE buffer (no dt aliasing -> loads pipeline past stores); B/C in LDS.
__global__ __launch_bounds__(256) void scan_pass3(const bf16* __restrict__ dt,
                                                  const bf16* __restrict__ xc,
                                                  const bf16* __restrict__ xz,
                                                  const float* __restrict__ dbc,
                                                  const float* __restrict__ An,
                                                  const int* __restrict__ flags,
                                                  const float* __restrict__ H0,
                                                  const float* __restrict__ Dp,
                                                  bf16* __restrict__ yg) {
  __shared__ __align__(16) float sbc[CL * 32];
  const int tid = threadIdx.x;
  const int e = blockIdx.x * 256 + tid;
  const int ch = blockIdx.y, b = blockIdx.z;
  const size_t posBase = (size_t)b * SEQ + (size_t)ch * CL;
  {
    const int il = tid >> 3, f = (tid & 7) * 4;
    gl2lds16(dbc + (posBase + il) * 48 + 16 + f, (char*)sbc + tid * 16);
  }
  const int fast = flags[e];
  float h[16];
  const float* hp = H0 + ((size_t)(b * NC + ch) * DI + e) * 16;
#pragma unroll
  for (int s = 0; s < 16; s += 4) {
    float4 h4 = *(const float4*)(hp + s);
    h[s] = h4.x; h[s + 1] = h4.y; h[s + 2] = h4.z; h[s + 3] = h4.w;
  }
  const float Dv = Dp[e];
  const float A0 = An[(size_t)e * 16];
  float A[16];
  if (!fast) {
#pragma unroll
    for (int s = 0; s < 16; s += 4) {
      float4 a4 = *(const float4*)(An + (size_t)e * 16 + s);
      A[s] = a4.x; A[s + 1] = a4.y; A[s + 2] = a4.z; A[s + 3] = a4.w;
    }
  }
  __syncthreads();
  if (fast) {
#pragma unroll 2
    for (int il = 0; il < CL; il++) {
      const size_t pos = posBase + il;
      const float dtv = (float)dt[pos * DI + e];
      const float xv = (float)xc[pos * DI + e];
      const float zv = (float)xz[pos * 1024 + DI + e];
      const float dtx = dtv * xv;
      float P[16];
      powtree(exp2_(dtv * A0), P);
      const float* bc = sbc + il * 32;
      float y0 = 0.f, y1 = 0.f, y2 = 0.f, y3 = 0.f;
#pragma unroll
      for (int sg = 0; sg < 4; sg++) {
        const float4 B4 = *(const float4*)(bc + sg * 4);
        const float4 C4 = *(const float4*)(bc + 16 + sg * 4);
        h[sg * 4 + 0] = P[sg * 4 + 0] * h[sg * 4 + 0] + dtx * B4.x;  y0 += h[sg * 4 + 0] * C4.x;
        h[sg * 4 + 1] = P[sg * 4 + 1] * h[sg * 4 + 1] + dtx * B4.y;  y1 += h[sg * 4 + 1] * C4.y;
        h[sg * 4 + 2] = P[sg * 4 + 2] * h[sg * 4 + 2] + dtx * B4.z;  y2 += h[sg * 4 + 2] * C4.z;
        h[sg * 4 + 3] = P[sg * 4 + 3] * h[sg * 4 + 3] + dtx * B4.w;  y3 += h[sg * 4 + 3] * C4.w;
      }
      const float y = (y0 + y1) + (y2 + y3);
      const float yv = (y + Dv * xv) * zv * sigmoidf_(zv);
      yg[pos * DI + e] = (bf16)yv;
    }
  } else {
#pragma unroll 2
    for (int il = 0; il < CL; il++) {
      const size_t pos = posBase + il;
      const float dtv = (float)dt[pos * DI + e];
      const float xv = (float)xc[pos * DI + e];
      const float zv = (float)xz[pos * 1024 + DI + e];
      const float dtx = dtv * xv;
      const float* bc = sbc + il * 32;
      float y = 0.f;
#pragma unroll
      for (int s = 0; s < 16; s++) {
        h[s] = exp2_(dtv * A[s]) * h[s] + dtx * bc[s];
        y += h[s] * bc[16 + s];
      }
      const float yv = (y + Dv * xv) * zv * sigmoidf_(zv);
      yg[pos * DI + e] = (bf16)yv;
    }
  }
}

// =================== host ===================
extern "C" void kernel_launch(void* const* d_in, const int* in_sizes, int n_in,
                              void* d_out, int out_size, void* d_ws, size_t ws_size,
                              hipStream_t stream) {
  const float* x = (const float*)d_in[0];
  const float* ln_w = (const float*)d_in[1];
  const float* ln_b = (const float*)d_in[2];
  const float* w_in = (const float*)d_in[3];
  const float* conv_w = (const float*)d_in[4];
  const float* conv_b = (const float*)d_in[5];
  const float* w_x = (const float*)d_in[6];
  const float* w_dt = (const float*)d_in[7];
  const float* b_dt = (const float*)d_in[8];
  const float* a_log = (const float*)d_in[9];
  const float* d_par = (const float*)d_in[10];
  const float* w_out = (const float*)d_in[11];

  char* ws = (char*)d_ws;
  size_t off = 0;
  auto alloc = [&](size_t bytes) {
    void* p = ws + off;
    off = (off + bytes + 255) & ~(size_t)255;
    return p;
  };
  bf16* xn = (bf16*)alloc((size_t)M * DM * 2);
  bf16* xzb = (bf16*)alloc((size_t)M * 1024 * 2);
  bf16* xcb = (bf16*)alloc((size_t)M * DI * 2);
  float* dbc = (float*)alloc((size_t)M * 48 * 4);
  bf16* dtb_ = (bf16*)alloc((size_t)M * DI * 2);
  bf16* ygb = (bf16*)alloc((size_t)M * DI * 2);             // R8: separate (de-aliased from dt)
  float* U = (float*)alloc((size_t)BATCH * NC * DI * 16 * 4);  // 33.5 MB
  float* SD = (float*)alloc((size_t)BATCH * NC * DI * 4);      // 2.1 MB
  bf16* w1b = (bf16*)alloc(1024 * 256 * 2);
  bf16* wxb = (bf16*)alloc(48 * 512 * 2);
  bf16* wob = (bf16*)alloc(256 * 512 * 2);
  float* An = (float*)alloc(512 * 16 * 4);
  int* flags = (int*)alloc(512 * 4);

  constexpr int prep_n = 1024 * 256 + 48 * 512 + 256 * 512 + DI;
  prep_kernel<<<dim3((prep_n + 255) / 256), dim3(256), 0, stream>>>(w_in, w_x, w_out, a_log, w1b, wxb, wob, An, flags);
  ln_kernel<<<dim3(M / 4), dim3(256), 0, stream>>>(x, ln_w, ln_b, xn);
  gemm_nt<1024, 256, true, false><<<dim3(M / 128, 8), dim3(256), 0, stream>>>(xn, w1b, (void*)xzb, nullptr);
  conv_silu<<<dim3(SEQ / 8, BATCH), dim3(256), 0, stream>>>(xzb, conv_w, conv_b, xcb);
  gemm_xproj<<<dim3(M / 64), dim3(256), 0, stream>>>(xcb, wxb, dbc);
  dtproj_kernel<<<dim3(M / 64, 2), dim3(256), 0, stream>>>(dbc, w_dt, b_dt, dtb_);
  scan_pass1<<<dim3(2, NC, BATCH), dim3(256), 0, stream>>>(dtb_, xcb, dbc, An, flags, U, SD);
  scan_pass2<<<dim3(BATCH * DI * 16 / 256), dim3(256), 0, stream>>>(SD, U, An);
  scan_pass3<<<dim3(2, NC, BATCH), dim3(256), 0, stream>>>(dtb_, xcb, xzb, dbc, An, flags, U, d_par, ygb);
  gemm_nt<256, 512, false, true><<<dim3(M / 128, 2), dim3(256), 0, stream>>>(ygb, wob, d_out, x);
}

// Round 9
// 303.722 us; speedup vs baseline: 1.1792x; 1.0302x over previous
//
#include <hip/hip_runtime.h>
#include <cstdint>

#define DEVI __device__ __forceinline__

typedef __bf16 bf16;
typedef __bf16 bf16x8 __attribute__((ext_vector_type(8)));
typedef __bf16 bf16x4 __attribute__((ext_vector_type(4)));
typedef __bf16 bf16x2 __attribute__((ext_vector_type(2)));
typedef float floatx4 __attribute__((ext_vector_type(4)));
typedef float f32x2 __attribute__((ext_vector_type(2)));

constexpr int BATCH = 16, SEQ = 2048, DM = 256, DI = 512;
constexpr int M = BATCH * SEQ;   // 32768 rows
constexpr int NC = 64;           // scan chunks per sequence
constexpr int CL = SEQ / NC;     // 32 steps per chunk
static_assert(NC * CL == SEQ, "chunking");
constexpr float LOG2E = 1.4426950408889634f;

// ---- async global->LDS (16B per lane, wave-uniform base + lane*16) ----
DEVI void gl2lds16(const void* g, void* l) {
  __builtin_amdgcn_global_load_lds(
      (const __attribute__((address_space(1))) unsigned int*)(uintptr_t)g,
      (__attribute__((address_space(3))) unsigned int*)(unsigned int)(uintptr_t)l,
      16, 0, 0);
}

DEVI float sigmoidf_(float x) { return 1.f / (1.f + __expf(-x)); }
// native v_exp_f32 (computes 2^x). NOTE: "__exp2f" collides with glibc math.h macros.
DEVI float exp2_(float x) { return __builtin_amdgcn_exp2f(x); }

// =================== prep: weights fp32 -> bf16, A2 = -exp(A_log)*log2e, power-law flag ===================
__global__ __launch_bounds__(256) void prep_kernel(
    const float* __restrict__ w1, const float* __restrict__ wx,
    const float* __restrict__ wo, const float* __restrict__ alog,
    bf16* __restrict__ w1b, bf16* __restrict__ wxb, bf16* __restrict__ wob,
    float* __restrict__ An, int* __restrict__ flags) {
  constexpr int n1 = 1024 * 256, n2 = 48 * 512, n3 = 256 * 512;
  int i = blockIdx.x * 256 + threadIdx.x;
  if (i < n1) w1b[i] = (bf16)w1[i];
  else if (i < n1 + n2) wxb[i - n1] = (bf16)wx[i - n1];
  else if (i < n1 + n2 + n3) wob[i - n1 - n2] = (bf16)wo[i - n1 - n2];
  else if (i < n1 + n2 + n3 + DI) {
    const int e = i - (n1 + n2 + n3);
    const float a0 = -__expf(alog[e * 16]);
    bool ok = (a0 < 0.f);
#pragma unroll 1
    for (int s = 0; s < 16; s++) {
      const float a = -__expf(alog[e * 16 + s]);
      An[e * 16 + s] = a * LOG2E;
      ok = ok && (__builtin_fabsf(a / a0 - (float)(s + 1)) < 1e-3f);
    }
    flags[e] = ok ? 1 : 0;
  }
}

// =================== LayerNorm: one wave per 256-col row, bf16 out ===================
__global__ __launch_bounds__(256) void ln_kernel(
    const float* __restrict__ x, const float* __restrict__ w,
    const float* __restrict__ b, bf16* __restrict__ xn) {
  const int row = blockIdx.x * 4 + (threadIdx.x >> 6);
  const int lane = threadIdx.x & 63;
  const float4 v = ((const float4*)(x + (size_t)row * DM))[lane];
  float s = v.x + v.y + v.z + v.w;
  float s2 = v.x * v.x + v.y * v.y + v.z * v.z + v.w * v.w;
#pragma unroll
  for (int m = 1; m < 64; m <<= 1) { s += __shfl_xor(s, m); s2 += __shfl_xor(s2, m); }
  const float mu = s * (1.f / DM);
  const float var = s2 * (1.f / DM) - mu * mu;
  const float rs = rsqrtf(var + 1e-5f);
  const float4 wv = ((const float4*)w)[lane];
  const float4 bv = ((const float4*)b)[lane];
  bf16x4 o;
  o[0] = (bf16)((v.x - mu) * rs * wv.x + bv.x);
  o[1] = (bf16)((v.y - mu) * rs * wv.y + bv.y);
  o[2] = (bf16)((v.z - mu) * rs * wv.z + bv.z);
  o[3] = (bf16)((v.w - mu) * rs * wv.w + bv.w);
  *(bf16x4*)(xn + (size_t)row * DM + lane * 4) = o;
}

// =================== NT bf16 GEMM: C[M,N] = A[M,K] * W[N,K]^T (m97 structure) ===================
template <int N, int K, bool OUT_BF16, bool RESID>
__global__ __launch_bounds__(256) void gemm_nt(const bf16* __restrict__ A,
                                               const bf16* __restrict__ W,
                                               void* __restrict__ out,
                                               const float* __restrict__ resid) {
  constexpr int BK = 32;
  __shared__ __align__(16) bf16 lA[128 * BK];
  __shared__ __align__(16) bf16 lB[128 * BK];
  const int tid = threadIdx.x;
  const int wave = tid >> 6, lane = tid & 63;
  const int bm = blockIdx.x * 128, bn = blockIdx.y * 128;
  const int wm = (wave >> 1) * 64, wn = (wave & 1) * 64;
  const int q = lane >> 4, r = lane & 15;
  floatx4 acc[4][4] = {};
  const int c0 = wave * 64 + lane;
  const int row0 = c0 >> 2, kp = (c0 & 3) * 8;
  for (int k0 = 0; k0 < K; k0 += BK) {
    gl2lds16(A + (size_t)(bm + row0) * K + k0 + kp, lA + c0 * 8);
    gl2lds16(A + (size_t)(bm + row0 + 64) * K + k0 + kp, lA + (c0 + 256) * 8);
    gl2lds16(W + (size_t)(bn + row0) * K + k0 + kp, lB + c0 * 8);
    gl2lds16(W + (size_t)(bn + row0 + 64) * K + k0 + kp, lB + (c0 + 256) * 8);
    __syncthreads();
    bf16x8 af[4], bfr[4];
#pragma unroll
    for (int i = 0; i < 4; i++) af[i] = *(const bf16x8*)&lA[(wm + i * 16 + r) * BK + q * 8];
#pragma unroll
    for (int j = 0; j < 4; j++) bfr[j] = *(const bf16x8*)&lB[(wn + j * 16 + r) * BK + q * 8];
#pragma unroll
    for (int i = 0; i < 4; i++)
#pragma unroll
      for (int j = 0; j < 4; j++)
        acc[i][j] = __builtin_amdgcn_mfma_f32_16x16x32_bf16(af[i], bfr[j], acc[i][j], 0, 0, 0);
    __syncthreads();
  }
#pragma unroll
  for (int i = 0; i < 4; i++)
#pragma unroll
    for (int j = 0; j < 4; j++)
#pragma unroll
      for (int t = 0; t < 4; t++) {
        const int row = bm + wm + i * 16 + q * 4 + t;
        const int col = bn + wn + j * 16 + r;
        const size_t idx = (size_t)row * N + col;
        float v = acc[i][j][t];
        if constexpr (OUT_BF16) {
          ((bf16*)out)[idx] = (bf16)v;
        } else {
          if constexpr (RESID) v += resid[idx];
          ((float*)out)[idx] = v;
        }
      }
}

// =================== causal depthwise conv(4) + SiLU ===================
// thread = 2 adjacent e (packed 4B coalesced loads), 8 positions/thread.
__global__ __launch_bounds__(256) void conv_silu(const bf16* __restrict__ xz,
                                                 const float* __restrict__ cw,
                                                 const float* __restrict__ cb,
                                                 bf16* __restrict__ xc) {
  const int tid = threadIdx.x;
  const int e2 = tid * 2;              // [0,512) in steps of 2
  const int p0 = blockIdx.x * 8;
  const int b = blockIdx.y;
  const float4 w0 = ((const float4*)cw)[e2];
  const float4 w1 = ((const float4*)cw)[e2 + 1];
  const float2 bias = *(const float2*)(cb + e2);
  float xa[11], xb_[11];
#pragma unroll
  for (int j = 0; j < 11; j++) {
    const int pos = p0 - 3 + j;
    float fa = 0.f, fb = 0.f;
    if (pos >= 0) {  // block-uniform (only blockIdx.x==0 has pos<0)
      const unsigned u = *(const unsigned*)(xz + ((size_t)b * SEQ + pos) * 1024 + e2);
      fa = __uint_as_float(u << 16);
      fb = __uint_as_float(u & 0xFFFF0000u);
    }
    xa[j] = fa; xb_[j] = fb;
  }
#pragma unroll
  for (int k = 0; k < 8; k++) {
    const float a0 = bias.x + xa[k] * w0.x + xa[k + 1] * w0.y + xa[k + 2] * w0.z + xa[k + 3] * w0.w;
    const float a1 = bias.y + xb_[k] * w1.x + xb_[k + 1] * w1.y + xb_[k + 2] * w1.z + xb_[k + 3] * w1.w;
    bf16x2 o;
    o[0] = (bf16)(a0 * sigmoidf_(a0));
    o[1] = (bf16)(a1 * sigmoidf_(a1));
    *(bf16x2*)(xc + ((size_t)b * SEQ + p0 + k) * DI + e2) = o;
  }
}

// =================== x_proj: dbc[M,48] = xc[M,512] * Wx[48,512]^T ===================
// 64-row tiles (512 blocks), wave = 16 rows x 48 cols.
__global__ __launch_bounds__(256) void gemm_xproj(const bf16* __restrict__ A,
                                                  const bf16* __restrict__ W,
                                                  float* __restrict__ out) {
  constexpr int K = DI;
  __shared__ __align__(16) bf16 lW[48 * K];   // 49152 B
  __shared__ __align__(16) bf16 lA[64 * 32];  // 4096 B
  const int tid = threadIdx.x;
  const int wave = tid >> 6, lane = tid & 63;
  const int bm = blockIdx.x * 64;
  const int q = lane >> 4, r = lane & 15;
#pragma unroll
  for (int rd = 0; rd < 12; rd++) {  // 3072 chunks of 16B
    const int c = rd * 256 + tid;
    gl2lds16((const char*)W + (size_t)c * 16, (char*)lW + (size_t)c * 16);
  }
  const int row0 = tid >> 2, kp = (tid & 3) * 8;
  const int wm = wave * 16;
  floatx4 acc[3] = {};
  for (int k0 = 0; k0 < K; k0 += 32) {
    gl2lds16(A + (size_t)(bm + row0) * K + k0 + kp, lA + tid * 8);
    __syncthreads();
    bf16x8 af = *(const bf16x8*)&lA[(wm + r) * 32 + q * 8];
#pragma unroll
    for (int j = 0; j < 3; j++) {
      const bf16x8 bfr = *(const bf16x8*)&lW[(j * 16 + r) * K + k0 + q * 8];
      acc[j] = __builtin_amdgcn_mfma_f32_16x16x32_bf16(af, bfr, acc[j], 0, 0, 0);
    }
    __syncthreads();
  }
#pragma unroll
  for (int j = 0; j < 3; j++)
#pragma unroll
    for (int t = 0; t < 4; t++)
      out[(size_t)(bm + wm + q * 4 + t) * 48 + j * 16 + r] = acc[j][t];
}

// =================== dt_proj (K=16) + softplus -> bf16 ===================
__global__ __launch_bounds__(256) void dtproj_kernel(const float* __restrict__ dbc,
                                                     const float* __restrict__ dtw,
                                                     const float* __restrict__ dtb,
                                                     bf16* __restrict__ dt) {
  __shared__ __align__(16) float sd[64 * 16];
  const int tid = threadIdx.x;
  const int p0 = blockIdx.x * 64;
  const int e = blockIdx.y * 256 + tid;
  {
    const int rowi = tid >> 2, coli = (tid & 3) * 4;
    *(float4*)&sd[rowi * 16 + coli] = *(const float4*)(dbc + (size_t)(p0 + rowi) * 48 + coli);
  }
  float w[16];
#pragma unroll
  for (int s = 0; s < 16; s += 4) {
    float4 t4 = *(const float4*)(dtw + (size_t)e * 16 + s);
    w[s] = t4.x; w[s + 1] = t4.y; w[s + 2] = t4.z; w[s + 3] = t4.w;
  }
  const float bias = dtb[e];
  __syncthreads();
  for (int p = 0; p < 64; p++) {
    float s = bias;
#pragma unroll
    for (int r2 = 0; r2 < 16; r2++) s += sd[p * 16 + r2] * w[r2];
    const float sp = (s > 15.f) ? s : __logf(1.f + __expf(s));
    dt[(size_t)(p0 + p) * DI + e] = (bf16)sp;
  }
}

// ---- packed power pairs: P[k] = {d1^(2k+1), d1^(2k+2)}, k=0..7 ----
DEVI void powpairs(float d1, f32x2* P) {
  const float d2 = d1 * d1;
  f32x2 d2s; d2s[0] = d2; d2s[1] = d2;
  const f32x2 d4s = d2s * d2s;
  const f32x2 d8s = d4s * d4s;
  P[0][0] = d1; P[0][1] = d2;
  P[1] = P[0] * d2s;
  P[2] = P[0] * d4s;
  P[3] = P[1] * d4s;
  P[4] = P[0] * d8s;
  P[5] = P[1] * d8s;
  P[6] = P[2] * d8s;
  P[7] = P[3] * d8s;
}

// =================== scan pass1: per-chunk aggregates (B staged in LDS; packed f32 math) ===================
__global__ __launch_bounds__(256) void scan_pass1(const bf16* __restrict__ dt,
                                                  const bf16* __restrict__ xc,
                                                  const float* __restrict__ dbc,
                                                  const float* __restrict__ An,
                                                  const int* __restrict__ flags,
                                                  float* __restrict__ U,
                                                  float* __restrict__ SD) {
  __shared__ __align__(16) float sbc[CL * 16];  // per pos: B[16]
  const int tid = threadIdx.x;
  const int e = blockIdx.x * 256 + tid;
  const int ch = blockIdx.y, b = blockIdx.z;
  const size_t posBase = (size_t)b * SEQ + (size_t)ch * CL;
  if (tid < CL * 4) {  // wave-uniform for waves 0..1
    const int il = tid >> 2, f = (tid & 3) * 4;
    gl2lds16(dbc + (posBase + il) * 48 + 16 + f, (char*)sbc + tid * 16);
  }
  const int fast = flags[e];
  f32x2 h2[8];
#pragma unroll
  for (int k = 0; k < 8; k++) { h2[k][0] = 0.f; h2[k][1] = 0.f; }
  float sdt = 0.f;
  const float A0 = An[(size_t)e * 16];
  float A[16];
  if (!fast) {
#pragma unroll
    for (int s = 0; s < 16; s += 4) {
      float4 a4 = *(const float4*)(An + (size_t)e * 16 + s);
      A[s] = a4.x; A[s + 1] = a4.y; A[s + 2] = a4.z; A[s + 3] = a4.w;
    }
  }
  __syncthreads();
  if (fast) {
    for (int il = 0; il < CL; il++) {
      const size_t pos = posBase + il;
      const float dtv = (float)dt[pos * DI + e];
      const float xv = (float)xc[pos * DI + e];
      const float dtx = dtv * xv;
      sdt += dtv;
      f32x2 P[8];
      powpairs(exp2_(dtv * A0), P);
      f32x2 dtx2; dtx2[0] = dtx; dtx2[1] = dtx;
      const float4* bb = (const float4*)(sbc + il * 16);
#pragma unroll
      for (int g = 0; g < 4; g++) {
        const float4 B4 = bb[g];
        f32x2 blo; blo[0] = B4.x; blo[1] = B4.y;
        f32x2 bhi; bhi[0] = B4.z; bhi[1] = B4.w;
        h2[2 * g] = P[2 * g] * h2[2 * g] + dtx2 * blo;
        h2[2 * g + 1] = P[2 * g + 1] * h2[2 * g + 1] + dtx2 * bhi;
      }
    }
  } else {
    for (int il = 0; il < CL; il++) {
      const size_t pos = posBase + il;
      const float dtv = (float)dt[pos * DI + e];
      const float xv = (float)xc[pos * DI + e];
      const float dtx = dtv * xv;
      sdt += dtv;
      const float* bc = sbc + il * 16;
#pragma unroll
      for (int s = 0; s < 16; s++) {
        const float hh = exp2_(dtv * A[s]) * h2[s >> 1][s & 1] + dtx * bc[s];
        h2[s >> 1][s & 1] = hh;
      }
    }
  }
  float* up = U + ((size_t)(b * NC + ch) * DI + e) * 16;
#pragma unroll
  for (int k = 0; k < 8; k += 2) {
    float4 o; o.x = h2[k][0]; o.y = h2[k][1]; o.z = h2[k + 1][0]; o.w = h2[k + 1][1];
    *(float4*)(up + k * 2) = o;
  }
  SD[(size_t)(b * NC + ch) * DI + e] = sdt;
}

// =================== scan pass2: combine chunk aggregates, parallel over (b,e,s) ===================
__global__ __launch_bounds__(256) void scan_pass2(const float* __restrict__ SD,
                                                  float* U,
                                                  const float* __restrict__ An) {
  const int t = blockIdx.x * 256 + threadIdx.x;  // over BATCH*DI*16
  const int s = t & 15;
  const int e = (t >> 4) & (DI - 1);
  const int b = t >> 13;
  const float A = An[e * 16 + s];  // pre-scaled by log2e
  float h = 0.f;
#pragma unroll 4
  for (int c = 0; c < NC; c++) {
    const size_t cell = (size_t)(b * NC + c) * DI + e;
    const float sdv = SD[cell];
    const size_t base = cell * 16 + s;
    const float u = U[base];
    const float h0 = h;
    h = exp2_(A * sdv) * h0 + u;
    U[base] = h0;
  }
}

// =================== scan pass3: replay chunk from true h0, emit gated y (packed f32 math) ===================
__global__ __launch_bounds__(256) void scan_pass3(const bf16* __restrict__ dt,
                                                  const bf16* __restrict__ xc,
                                                  const bf16* __restrict__ xz,
                                                  const float* __restrict__ dbc,
                                                  const float* __restrict__ An,
                                                  const int* __restrict__ flags,
                                                  const float* __restrict__ H0,
                                                  const float* __restrict__ Dp,
                                                  bf16* __restrict__ yg) {
  __shared__ __align__(16) float sbc[CL * 32];  // per pos: B[16] C[16]
  const int tid = threadIdx.x;
  const int e = blockIdx.x * 256 + tid;
  const int ch = blockIdx.y, b = blockIdx.z;
  const size_t posBase = (size_t)b * SEQ + (size_t)ch * CL;
  {
    const int il = tid >> 3, f = (tid & 7) * 4;
    gl2lds16(dbc + (posBase + il) * 48 + 16 + f, (char*)sbc + tid * 16);
  }
  const int fast = flags[e];
  f32x2 h2[8];
  const float* hp = H0 + ((size_t)(b * NC + ch) * DI + e) * 16;
#pragma unroll
  for (int k = 0; k < 8; k += 2) {
    const float4 h4 = *(const float4*)(hp + k * 2);
    h2[k][0] = h4.x; h2[k][1] = h4.y; h2[k + 1][0] = h4.z; h2[k + 1][1] = h4.w;
  }
  const float Dv = Dp[e];
  const float A0 = An[(size_t)e * 16];
  float A[16];
  if (!fast) {
#pragma unroll
    for (int s = 0; s < 16; s += 4) {
      float4 a4 = *(const float4*)(An + (size_t)e * 16 + s);
      A[s] = a4.x; A[s + 1] = a4.y; A[s + 2] = a4.z; A[s + 3] = a4.w;
    }
  }
  __syncthreads();
  if (fast) {
    for (int il = 0; il < CL; il++) {
      const size_t pos = posBase + il;
      const float dtv = (float)dt[pos * DI + e];
      const float xv = (float)xc[pos * DI + e];
      const float zv = (float)xz[pos * 1024 + DI + e];
      const float dtx = dtv * xv;
      f32x2 P[8];
      powpairs(exp2_(dtv * A0), P);
      f32x2 dtx2; dtx2[0] = dtx; dtx2[1] = dtx;
      const float4* bb = (const float4*)(sbc + il * 32);
      f32x2 ya; ya[0] = 0.f; ya[1] = 0.f;
      f32x2 yb; yb[0] = 0.f; yb[1] = 0.f;
#pragma unroll
      for (int g = 0; g < 4; g++) {
        const float4 B4 = bb[g];
        const float4 C4 = bb[4 + g];
        f32x2 blo; blo[0] = B4.x; blo[1] = B4.y;
        f32x2 bhi; bhi[0] = B4.z; bhi[1] = B4.w;
        f32x2 clo; clo[0] = C4.x; clo[1] = C4.y;
        f32x2 chi; chi[0] = C4.z; chi[1] = C4.w;
        h2[2 * g] = P[2 * g] * h2[2 * g] + dtx2 * blo;
        h2[2 * g + 1] = P[2 * g + 1] * h2[2 * g + 1] + dtx2 * bhi;
        ya = ya + h2[2 * g] * clo;
        yb = yb + h2[2 * g + 1] * chi;
      }
      const f32x2 ys = ya + yb;
      const float y = ys[0] + ys[1];
      const float yv = (y + Dv * xv) * zv * sigmoidf_(zv);
      yg[pos * DI + e] = (bf16)yv;
    }
  } else {
    for (int il = 0; il < CL; il++) {
      const size_t pos = posBase + il;
      const float dtv = (float)dt[pos * DI + e];
      const float xv = (float)xc[pos * DI + e];
      const float zv = (float)xz[pos * 1024 + DI + e];
      const float dtx = dtv * xv;
      const float* bc = sbc + il * 32;
      float y = 0.f;
#pragma unroll
      for (int s = 0; s < 16; s++) {
        const float hh = exp2_(dtv * A[s]) * h2[s >> 1][s & 1] + dtx * bc[s];
        h2[s >> 1][s & 1] = hh;
        y += hh * bc[16 + s];
      }
      const float yv = (y + Dv * xv) * zv * sigmoidf_(zv);
      yg[pos * DI + e] = (bf16)yv;
    }
  }
}

// =================== host ===================
extern "C" void kernel_launch(void* const* d_in, const int* in_sizes, int n_in,
                              void* d_out, int out_size, void* d_ws, size_t ws_size,
                              hipStream_t stream) {
  const float* x = (const float*)d_in[0];
  const float* ln_w = (const float*)d_in[1];
  const float* ln_b = (const float*)d_in[2];
  const float* w_in = (const float*)d_in[3];
  const float* conv_w = (const float*)d_in[4];
  const float* conv_b = (const float*)d_in[5];
  const float* w_x = (const float*)d_in[6];
  const float* w_dt = (const float*)d_in[7];
  const float* b_dt = (const float*)d_in[8];
  const float* a_log = (const float*)d_in[9];
  const float* d_par = (const float*)d_in[10];
  const float* w_out = (const float*)d_in[11];

  char* ws = (char*)d_ws;
  size_t off = 0;
  auto alloc = [&](size_t bytes) {
    void* p = ws + off;
    off = (off + bytes + 255) & ~(size_t)255;
    return p;
  };
  bf16* xn = (bf16*)alloc((size_t)M * DM * 2);
  bf16* xzb = (bf16*)alloc((size_t)M * 1024 * 2);
  bf16* xcb = (bf16*)alloc((size_t)M * DI * 2);
  float* dbc = (float*)alloc((size_t)M * 48 * 4);
  bf16* dtb_ = (bf16*)alloc((size_t)M * DI * 2);
  bf16* ygb = (bf16*)alloc((size_t)M * DI * 2);
  float* U = (float*)alloc((size_t)BATCH * NC * DI * 16 * 4);  // 33.5 MB
  float* SD = (float*)alloc((size_t)BATCH * NC * DI * 4);      // 2.1 MB
  bf16* w1b = (bf16*)alloc(1024 * 256 * 2);
  bf16* wxb = (bf16*)alloc(48 * 512 * 2);
  bf16* wob = (bf16*)alloc(256 * 512 * 2);
  float* An = (float*)alloc(512 * 16 * 4);
  int* flags = (int*)alloc(512 * 4);

  constexpr int prep_n = 1024 * 256 + 48 * 512 + 256 * 512 + DI;
  prep_kernel<<<dim3((prep_n + 255) / 256), dim3(256), 0, stream>>>(w_in, w_x, w_out, a_log, w1b, wxb, wob, An, flags);
  ln_kernel<<<dim3(M / 4), dim3(256), 0, stream>>>(x, ln_w, ln_b, xn);
  gemm_nt<1024, 256, true, false><<<dim3(M / 128, 8), dim3(256), 0, stream>>>(xn, w1b, (void*)xzb, nullptr);
  conv_silu<<<dim3(SEQ / 8, BATCH), dim3(256), 0, stream>>>(xzb, conv_w, conv_b, xcb);
  gemm_xproj<<<dim3(M / 64), dim3(256), 0, stream>>>(xcb, wxb, dbc);
  dtproj_kernel<<<dim3(M / 64, 2), dim3(256), 0, stream>>>(dbc, w_dt, b_dt, dtb_);
  scan_pass1<<<dim3(2, NC, BATCH), dim3(256), 0, stream>>>(dtb_, xcb, dbc, An, flags, U, SD);
  scan_pass2<<<dim3(BATCH * DI * 16 / 256), dim3(256), 0, stream>>>(SD, U, An);
  scan_pass3<<<dim3(2, NC, BATCH), dim3(256), 0, stream>>>(dtb_, xcb, xzb, dbc, An, flags, U, d_par, ygb);
  gemm_nt<256, 512, false, true><<<dim3(M / 128, 2), dim3(256), 0, stream>>>(ygb, wob, d_out, x);
}